// Round 1
// baseline (345.821 us; speedup 1.0000x reference)
//
#include <hip/hip_runtime.h>
#include <hip/hip_bf16.h>

#define DIM 768
#define NH 12
#define HD 64
#define B_ 8
#define N_ 1024
#define BH (B_*NH)
#define EPS 1e-5f
#define SCALE 0.125f

typedef short s16x8 __attribute__((ext_vector_type(8)));
typedef float f32x4 __attribute__((ext_vector_type(4)));

__device__ __forceinline__ unsigned short f2bf(float f) {
    union { float f; unsigned u; } v; v.f = f;
    unsigned r = v.u + 0x7fffu + ((v.u >> 16) & 1u);
    return (unsigned short)(r >> 16);
}

// ---------------- Kernel 1: LayerNorm q,k + pack v (transposed) ----------------
// grid: BH*16 blocks (each = one (b,h) and 64 n-rows), 256 threads
__global__ __launch_bounds__(256)
void ln_pack_kernel(const float* __restrict__ QKV,
                    const float* __restrict__ qw, const float* __restrict__ qb,
                    const float* __restrict__ kw, const float* __restrict__ kb,
                    unsigned short* __restrict__ Qn,
                    unsigned short* __restrict__ Kn,
                    unsigned short* __restrict__ Vt) {
    int bid = blockIdx.x;
    int bh = bid >> 4;
    int nt = bid & 15;
    int b = bh / NH, h = bh % NH;
    int n0 = nt * 64;
    int tid = threadIdx.x, w = tid >> 6, ln = tid & 63;

    __shared__ __attribute__((aligned(16))) unsigned short vlds[64][72];

    float qwv = qw[ln], qbv = qb[ln], kwv = kw[ln], kbv = kb[ln];

    for (int i = 0; i < 16; i++) {
        int nl = w * 16 + i;
        int n = n0 + nl;
        size_t base = ((size_t)(b * N_ + n)) * (3 * DIM) + h * HD;
        float q = QKV[base + ln];
        float k = QKV[base + DIM + ln];
        float v = QKV[base + 2 * DIM + ln];
        vlds[nl][ln] = f2bf(v);

        float s1 = q, s2 = q * q;
        #pragma unroll
        for (int off = 1; off < 64; off <<= 1) {
            s1 += __shfl_xor(s1, off, 64);
            s2 += __shfl_xor(s2, off, 64);
        }
        float mu = s1 * (1.0f / 64.0f);
        float var = s2 * (1.0f / 64.0f) - mu * mu;
        float qn = (q - mu) * rsqrtf(var + EPS) * qwv + qbv;
        Qn[((size_t)bh * N_ + n) * HD + ln] = f2bf(qn);

        s1 = k; s2 = k * k;
        #pragma unroll
        for (int off = 1; off < 64; off <<= 1) {
            s1 += __shfl_xor(s1, off, 64);
            s2 += __shfl_xor(s2, off, 64);
        }
        mu = s1 * (1.0f / 64.0f);
        var = s2 * (1.0f / 64.0f) - mu * mu;
        float kn = (k - mu) * rsqrtf(var + EPS) * kwv + kbv;
        Kn[((size_t)bh * N_ + n) * HD + ln] = f2bf(kn);
    }
    __syncthreads();
    // transpose-write V: thread t handles row d = t>>2, cols (t&3)*16 .. +15
    int d = tid >> 2, c0 = (tid & 3) * 16;
    s16x8 v0, v1;
    #pragma unroll
    for (int i = 0; i < 8; i++) {
        v0[i] = (short)vlds[c0 + i][d];
        v1[i] = (short)vlds[c0 + 8 + i][d];
    }
    size_t obase = ((size_t)bh * HD + d) * N_ + n0 + c0;
    *reinterpret_cast<s16x8*>(Vt + obase) = v0;
    *reinterpret_cast<s16x8*>(Vt + obase + 8) = v1;
}

// ---------------- Kernel 2: convert proj_w to bf16 ----------------
__global__ __launch_bounds__(256)
void cvt_kernel(const float* __restrict__ in, unsigned short* __restrict__ outp, int n) {
    int i = blockIdx.x * 256 + threadIdx.x;
    if (i < n) outp[i] = f2bf(in[i]);
}

// ---------------- Kernel 3: flash attention ----------------
// grid: BH * 8 blocks (each = (b,h) and 128 q-rows), 256 threads (4 waves x 32 rows)
__global__ __launch_bounds__(256)
void attn_kernel(const unsigned short* __restrict__ Qn,
                 const unsigned short* __restrict__ Kn,
                 const unsigned short* __restrict__ Vt,
                 unsigned short* __restrict__ Xb) {
    int bid = blockIdx.x;
    int bh = bid >> 3;
    int mt = bid & 7;
    int b = bh / NH, h = bh % NH;
    int tid = threadIdx.x;
    int w = tid >> 6;
    int ln = tid & 63;
    int l16 = ln & 15;
    int quad = ln >> 4;

    // padded strides: 72 (144B) and 56 (112B) keep 16B alignment, 2-way banks only
    __shared__ __attribute__((aligned(16))) unsigned short Kl[32][72];
    __shared__ __attribute__((aligned(16))) unsigned short Vl[64][56];
    __shared__ __attribute__((aligned(16))) unsigned short Pl[4][32][56];

    const unsigned short* Qbase = Qn + (size_t)bh * N_ * HD;
    const unsigned short* Kbase = Kn + (size_t)bh * N_ * HD;
    const unsigned short* Vbase = Vt + (size_t)bh * HD * N_;

    int m0 = mt * 128 + w * 32;
    s16x8 qf[2][2];
    #pragma unroll
    for (int si = 0; si < 2; si++)
        #pragma unroll
        for (int c = 0; c < 2; c++)
            qf[si][c] = *reinterpret_cast<const s16x8*>(
                Qbase + (size_t)(m0 + si * 16 + l16) * HD + c * 32 + quad * 8);

    f32x4 o[2][4];
    float mrow[2][4], lrow[2][4];
    #pragma unroll
    for (int si = 0; si < 2; si++) {
        #pragma unroll
        for (int t = 0; t < 4; t++) o[si][t] = (f32x4){0.f, 0.f, 0.f, 0.f};
        #pragma unroll
        for (int r = 0; r < 4; r++) { mrow[si][r] = -1e30f; lrow[si][r] = 0.f; }
    }

    for (int n0 = 0; n0 < N_; n0 += 32) {
        __syncthreads();
        {   // stage K tile (32 x 64) and V^T tile (64 x 32)
            int r = tid >> 3, c8 = (tid & 7) * 8;
            *reinterpret_cast<s16x8*>(&Kl[r][c8]) =
                *reinterpret_cast<const s16x8*>(Kbase + (size_t)(n0 + r) * HD + c8);
            int vr = tid >> 2, vc = (tid & 3) * 8;
            *reinterpret_cast<s16x8*>(&Vl[vr][vc]) =
                *reinterpret_cast<const s16x8*>(Vbase + (size_t)vr * N_ + n0 + vc);
        }
        __syncthreads();

        // S = Q K^T for 32x32 tile
        s16x8 kf[2][2];
        #pragma unroll
        for (int h2 = 0; h2 < 2; h2++)
            #pragma unroll
            for (int c = 0; c < 2; c++)
                kf[h2][c] = *reinterpret_cast<const s16x8*>(&Kl[h2 * 16 + l16][c * 32 + quad * 8]);

        f32x4 s[2][2];
        #pragma unroll
        for (int si = 0; si < 2; si++)
            #pragma unroll
            for (int h2 = 0; h2 < 2; h2++) {
                f32x4 a = (f32x4){0.f, 0.f, 0.f, 0.f};
                a = __builtin_amdgcn_mfma_f32_16x16x32_bf16(qf[si][0], kf[h2][0], a, 0, 0, 0);
                a = __builtin_amdgcn_mfma_f32_16x16x32_bf16(qf[si][1], kf[h2][1], a, 0, 0, 0);
                s[si][h2] = a;
            }

        // online softmax per row (rows quad*4+r, reduce across 16 lanes of quad)
        #pragma unroll
        for (int si = 0; si < 2; si++) {
            float mx[4], p0[4], p1[4], rs[4];
            #pragma unroll
            for (int r = 0; r < 4; r++) {
                float a0 = s[si][0][r] * SCALE, a1 = s[si][1][r] * SCALE;
                s[si][0][r] = a0; s[si][1][r] = a1;
                mx[r] = fmaxf(a0, a1);
            }
            #pragma unroll
            for (int off = 1; off < 16; off <<= 1)
                #pragma unroll
                for (int r = 0; r < 4; r++)
                    mx[r] = fmaxf(mx[r], __shfl_xor(mx[r], off, 64));
            #pragma unroll
            for (int r = 0; r < 4; r++) {
                float mn = fmaxf(mrow[si][r], mx[r]);
                float al = __expf(mrow[si][r] - mn);
                mrow[si][r] = mn;
                p0[r] = __expf(s[si][0][r] - mn);
                p1[r] = __expf(s[si][1][r] - mn);
                rs[r] = p0[r] + p1[r];
                lrow[si][r] *= al;
                #pragma unroll
                for (int t = 0; t < 4; t++) o[si][t][r] *= al;
                Pl[w][si * 16 + quad * 4 + r][l16] = f2bf(p0[r]);
                Pl[w][si * 16 + quad * 4 + r][16 + l16] = f2bf(p1[r]);
            }
            #pragma unroll
            for (int off = 1; off < 16; off <<= 1)
                #pragma unroll
                for (int r = 0; r < 4; r++)
                    rs[r] += __shfl_xor(rs[r], off, 64);
            #pragma unroll
            for (int r = 0; r < 4; r++) lrow[si][r] += rs[r];
        }
        __syncthreads();

        // O += P V  (P via LDS round trip: C-layout -> A-layout)
        s16x8 pf[2];
        #pragma unroll
        for (int si = 0; si < 2; si++)
            pf[si] = *reinterpret_cast<const s16x8*>(&Pl[w][si * 16 + l16][quad * 8]);
        #pragma unroll
        for (int t = 0; t < 4; t++) {
            s16x8 vf = *reinterpret_cast<const s16x8*>(&Vl[t * 16 + l16][quad * 8]);
            #pragma unroll
            for (int si = 0; si < 2; si++)
                o[si][t] = __builtin_amdgcn_mfma_f32_16x16x32_bf16(pf[si], vf, o[si][t], 0, 0, 0);
        }
    }

    // epilogue: normalize and store X in (B,N,H*D) layout as bf16
    #pragma unroll
    for (int si = 0; si < 2; si++)
        #pragma unroll
        for (int r = 0; r < 4; r++) {
            float inv = 1.0f / lrow[si][r];
            int m = m0 + si * 16 + quad * 4 + r;
            size_t row = (size_t)b * N_ + m;
            #pragma unroll
            for (int t = 0; t < 4; t++)
                Xb[row * DIM + h * HD + t * 16 + l16] = f2bf(o[si][t][r] * inv);
        }
}

// ---------------- Kernel 4: projection GEMM (8192x768x768) + bias ----------------
// grid: 128 * 12 blocks; block = 64x64 tile; wave = 32x32
__global__ __launch_bounds__(256)
void proj_kernel(const unsigned short* __restrict__ Xb,
                 const unsigned short* __restrict__ Wb,
                 const float* __restrict__ pb,
                 float* __restrict__ out) {
    int bid = blockIdx.x;
    int bm = bid % 128, bn = bid / 128;
    int tid = threadIdx.x, w = tid >> 6, ln = tid & 63;
    int l16 = ln & 15, quad = ln >> 4;
    int m0 = bm * 64 + (w & 1) * 32;
    int n0 = bn * 64 + (w >> 1) * 32;

    f32x4 c[2][2];
    #pragma unroll
    for (int i = 0; i < 2; i++)
        #pragma unroll
        for (int j = 0; j < 2; j++) c[i][j] = (f32x4){0.f, 0.f, 0.f, 0.f};

    for (int kk = 0; kk < DIM; kk += 32) {
        s16x8 af[2], bf[2];
        #pragma unroll
        for (int i = 0; i < 2; i++)
            af[i] = *reinterpret_cast<const s16x8*>(
                Xb + (size_t)(m0 + i * 16 + l16) * DIM + kk + quad * 8);
        #pragma unroll
        for (int j = 0; j < 2; j++)
            bf[j] = *reinterpret_cast<const s16x8*>(
                Wb + (size_t)(n0 + j * 16 + l16) * DIM + kk + quad * 8);
        #pragma unroll
        for (int i = 0; i < 2; i++)
            #pragma unroll
            for (int j = 0; j < 2; j++)
                c[i][j] = __builtin_amdgcn_mfma_f32_16x16x32_bf16(af[i], bf[j], c[i][j], 0, 0, 0);
    }

    #pragma unroll
    for (int j = 0; j < 2; j++) {
        float bias = pb[n0 + j * 16 + l16];
        #pragma unroll
        for (int i = 0; i < 2; i++)
            #pragma unroll
            for (int r = 0; r < 4; r++) {
                int row = m0 + i * 16 + quad * 4 + r;
                out[(size_t)row * DIM + n0 + j * 16 + l16] = c[i][j][r] + bias;
            }
    }
}

extern "C" void kernel_launch(void* const* d_in, const int* in_sizes, int n_in,
                              void* d_out, int out_size, void* d_ws, size_t ws_size,
                              hipStream_t stream) {
    const float* QKV = (const float*)d_in[0];
    const float* qw  = (const float*)d_in[1];
    const float* qb  = (const float*)d_in[2];
    const float* kw  = (const float*)d_in[3];
    const float* kb  = (const float*)d_in[4];
    const float* pw  = (const float*)d_in[5];
    const float* pb  = (const float*)d_in[6];
    float* out = (float*)d_out;

    unsigned short* Qn = (unsigned short*)d_ws;                 // 96*1024*64
    unsigned short* Kn = Qn + (size_t)BH * N_ * HD;
    unsigned short* Vt = Kn + (size_t)BH * N_ * HD;
    unsigned short* Xb = Vt + (size_t)BH * N_ * HD;             // 8192*768
    unsigned short* Wb = Xb + (size_t)B_ * N_ * DIM;            // 768*768

    ln_pack_kernel<<<BH * 16, 256, 0, stream>>>(QKV, qw, qb, kw, kb, Qn, Kn, Vt);
    cvt_kernel<<<(DIM * DIM + 255) / 256, 256, 0, stream>>>(pw, Wb, DIM * DIM);
    attn_kernel<<<BH * 8, 256, 0, stream>>>(Qn, Kn, Vt, Xb);
    proj_kernel<<<128 * 12, 256, 0, stream>>>(Xb, Wb, pb, out);
}

// Round 2
// 292.762 us; speedup vs baseline: 1.1812x; 1.1812x over previous
//
#include <hip/hip_runtime.h>
#include <hip/hip_bf16.h>

#define DIM 768
#define NH 12
#define HD 64
#define B_ 8
#define N_ 1024
#define BH (B_*NH)
#define EPS 1e-5f
// fold 1/sqrt(64) * log2(e) into q at pack time -> scores arrive in exp2 domain
#define QSCALE 0.18033688011112042f

typedef short s16x8 __attribute__((ext_vector_type(8)));
typedef float f32x4 __attribute__((ext_vector_type(4)));

__device__ __forceinline__ unsigned pk2bf(float a, float b) {
    __hip_bfloat162 h = __float22bfloat162_rn(float2{a, b});
    union { __hip_bfloat162 h; unsigned u; } cv; cv.h = h;
    return cv.u;
}

__device__ __forceinline__ float fexp2(float x) {
#if __has_builtin(__builtin_amdgcn_exp2f)
    return __builtin_amdgcn_exp2f(x);
#else
    return exp2f(x);
#endif
}

// ---------------- Kernel 1: LayerNorm q,k + pack v (transposed) ----------------
// grid: BH*16 blocks (one (b,h), 64 n-rows each), 256 threads
__global__ __launch_bounds__(256)
void ln_pack_kernel(const float* __restrict__ QKV,
                    const float* __restrict__ qw, const float* __restrict__ qb,
                    const float* __restrict__ kw, const float* __restrict__ kb,
                    unsigned short* __restrict__ Qn,
                    unsigned short* __restrict__ Kn,
                    unsigned short* __restrict__ Vt) {
    int bid = blockIdx.x;
    int bh = bid >> 4, nt = bid & 15;
    int b = bh / NH, h = bh % NH;
    int n0 = nt * 64;
    int tid = threadIdx.x, w = tid >> 6, ln = tid & 63;
    int sr = ln >> 4, part = ln & 15;

    __shared__ __attribute__((aligned(16))) unsigned short vlds[64][72];

    float4 qwv = *(const float4*)(qw + part * 4);
    float4 qbv = *(const float4*)(qb + part * 4);
    float4 kwv = *(const float4*)(kw + part * 4);
    float4 kbv = *(const float4*)(kb + part * 4);

    #pragma unroll
    for (int it = 0; it < 4; it++) {
        int rl = w * 16 + it * 4 + sr;   // local row 0..63
        int n = n0 + rl;
        size_t base = ((size_t)(b * N_ + n)) * (3 * DIM) + h * HD + part * 4;
        float4 q = *(const float4*)(QKV + base);
        float4 k = *(const float4*)(QKV + base + DIM);
        float4 v = *(const float4*)(QKV + base + 2 * DIM);

        { uint2 u; u.x = pk2bf(v.x, v.y); u.y = pk2bf(v.z, v.w);
          *(uint2*)&vlds[rl][part * 4] = u; }

        float s1 = q.x + q.y + q.z + q.w;
        float s2 = q.x * q.x + q.y * q.y + q.z * q.z + q.w * q.w;
        float t1 = k.x + k.y + k.z + k.w;
        float t2 = k.x * k.x + k.y * k.y + k.z * k.z + k.w * k.w;
        #pragma unroll
        for (int m = 1; m < 16; m <<= 1) {
            s1 += __shfl_xor(s1, m, 64);
            s2 += __shfl_xor(s2, m, 64);
            t1 += __shfl_xor(t1, m, 64);
            t2 += __shfl_xor(t2, m, 64);
        }
        float mu = s1 * (1.0f / 64.0f);
        float var = s2 * (1.0f / 64.0f) - mu * mu;
        float rstd = rsqrtf(var + EPS);
        float4 qn;
        qn.x = ((q.x - mu) * rstd * qwv.x + qbv.x) * QSCALE;
        qn.y = ((q.y - mu) * rstd * qwv.y + qbv.y) * QSCALE;
        qn.z = ((q.z - mu) * rstd * qwv.z + qbv.z) * QSCALE;
        qn.w = ((q.w - mu) * rstd * qwv.w + qbv.w) * QSCALE;
        { uint2 u; u.x = pk2bf(qn.x, qn.y); u.y = pk2bf(qn.z, qn.w);
          *(uint2*)(Qn + ((size_t)bh * N_ + n) * HD + part * 4) = u; }

        mu = t1 * (1.0f / 64.0f);
        var = t2 * (1.0f / 64.0f) - mu * mu;
        rstd = rsqrtf(var + EPS);
        float4 kn;
        kn.x = (k.x - mu) * rstd * kwv.x + kbv.x;
        kn.y = (k.y - mu) * rstd * kwv.y + kbv.y;
        kn.z = (k.z - mu) * rstd * kwv.z + kbv.z;
        kn.w = (k.w - mu) * rstd * kwv.w + kbv.w;
        { uint2 u; u.x = pk2bf(kn.x, kn.y); u.y = pk2bf(kn.z, kn.w);
          *(uint2*)(Kn + ((size_t)bh * N_ + n) * HD + part * 4) = u; }
    }
    __syncthreads();
    // transpose V out of LDS: thread t -> d = t>>2, 16-key segment t&3
    int d = tid >> 2, seg = tid & 3;
    s16x8 o0, o1;
    #pragma unroll
    for (int i = 0; i < 8; i++) {
        o0[i] = (short)vlds[seg * 16 + i][d];
        o1[i] = (short)vlds[seg * 16 + 8 + i][d];
    }
    size_t ob = ((size_t)bh * HD + d) * N_ + n0 + seg * 16;
    *(s16x8*)(Vt + ob) = o0;
    *(s16x8*)(Vt + ob + 8) = o1;
}

// ---------------- Kernel 2: convert proj_w to bf16 (vectorized) ----------------
__global__ __launch_bounds__(256)
void cvt_kernel(const float* __restrict__ in, unsigned short* __restrict__ outp, int n4) {
    int i = blockIdx.x * 256 + threadIdx.x;
    if (i < n4) {
        float4 f = *(const float4*)(in + (size_t)i * 4);
        uint2 u; u.x = pk2bf(f.x, f.y); u.y = pk2bf(f.z, f.w);
        *(uint2*)(outp + (size_t)i * 4) = u;
    }
}

// ---------------- Kernel 3: flash attention, S^T orientation, barrier-free ----------------
// grid: 768 blocks; bh = bid % 96 (XCD-local head), 128 q-rows per block, 4 waves x 32 rows
__global__ __launch_bounds__(256, 3)
void attn_kernel(const unsigned short* __restrict__ Qn,
                 const unsigned short* __restrict__ Kn,
                 const unsigned short* __restrict__ Vt,
                 unsigned short* __restrict__ Xb) {
    int bid = blockIdx.x;
    int bh = bid % BH;           // blocks of same head are 96 apart -> same XCD
    int mt = bid / BH;
    int b = bh / NH, h = bh % NH;
    int tid = threadIdx.x;
    int w = tid >> 6, ln = tid & 63;
    int l16 = ln & 15, quad = ln >> 4;

    __shared__ __attribute__((aligned(16))) unsigned short Pl[4][16][48];
    __shared__ __attribute__((aligned(16))) unsigned short Ol[4][16][72];

    const unsigned short* Qb = Qn + (size_t)bh * N_ * HD;
    const unsigned short* Kb = Kn + (size_t)bh * N_ * HD;
    const unsigned short* Vb = Vt + (size_t)bh * HD * N_;

    int m0 = mt * 128 + w * 32;

    // Q B-fragments (B[k=d][n=qrow=l16]); d = ch*32 + quad*8 + j
    s16x8 qf[2][2];
    #pragma unroll
    for (int si = 0; si < 2; si++)
        #pragma unroll
        for (int ch = 0; ch < 2; ch++)
            qf[si][ch] = *(const s16x8*)(Qb + (size_t)(m0 + si * 16 + l16) * HD + ch * 32 + quad * 8);

    f32x4 o[2][4];
    float mrow[2] = {-1e30f, -1e30f};
    float lp[2] = {0.f, 0.f};    // per-lane partial row-sum (quad-reduced at end)
    #pragma unroll
    for (int si = 0; si < 2; si++)
        #pragma unroll
        for (int t = 0; t < 4; t++) o[si][t] = (f32x4){0.f, 0.f, 0.f, 0.f};

    s16x8 kfA[2][2], vfA[4], kfB[2][2], vfB[4];

#define LOADK(dst, nn)                                                          \
    _Pragma("unroll") for (int kh = 0; kh < 2; kh++)                            \
        _Pragma("unroll") for (int ch = 0; ch < 2; ch++)                        \
            dst[kh][ch] = *(const s16x8*)(Kb + (size_t)((nn) + kh * 16 + l16) * HD + ch * 32 + quad * 8);
#define LOADV(dst, nn)                                                          \
    _Pragma("unroll") for (int t = 0; t < 4; t++)                               \
        dst[t] = *(const s16x8*)(Vb + (size_t)(t * 16 + l16) * N_ + (nn) + quad * 8);

#define PROCESS(kf, vf)                                                         \
    _Pragma("unroll") for (int si = 0; si < 2; si++) {                          \
        f32x4 st[2];                                                            \
        _Pragma("unroll") for (int kh = 0; kh < 2; kh++) {                      \
            f32x4 a = (f32x4){0.f, 0.f, 0.f, 0.f};                              \
            a = __builtin_amdgcn_mfma_f32_16x16x32_bf16(kf[kh][0], qf[si][0], a, 0, 0, 0); \
            a = __builtin_amdgcn_mfma_f32_16x16x32_bf16(kf[kh][1], qf[si][1], a, 0, 0, 0); \
            st[kh] = a;                                                         \
        }                                                                       \
        float mx = fmaxf(fmaxf(fmaxf(st[0][0], st[0][1]), fmaxf(st[0][2], st[0][3])), \
                         fmaxf(fmaxf(st[1][0], st[1][1]), fmaxf(st[1][2], st[1][3]))); \
        mx = fmaxf(mx, __shfl_xor(mx, 16, 64));                                 \
        mx = fmaxf(mx, __shfl_xor(mx, 32, 64));                                 \
        float mn = fmaxf(mrow[si], mx);                                         \
        float al = fexp2(mrow[si] - mn);                                        \
        mrow[si] = mn;                                                          \
        float p0 = fexp2(st[0][0] - mn), p1 = fexp2(st[0][1] - mn);             \
        float p2 = fexp2(st[0][2] - mn), p3 = fexp2(st[0][3] - mn);             \
        float p4 = fexp2(st[1][0] - mn), p5 = fexp2(st[1][1] - mn);             \
        float p6 = fexp2(st[1][2] - mn), p7 = fexp2(st[1][3] - mn);             \
        lp[si] = lp[si] * al + ((p0 + p1) + (p2 + p3)) + ((p4 + p5) + (p6 + p7)); \
        _Pragma("unroll") for (int t = 0; t < 4; t++) {                         \
            o[si][t][0] *= al; o[si][t][1] *= al; o[si][t][2] *= al; o[si][t][3] *= al; \
        }                                                                       \
        { uint2 u; u.x = pk2bf(p0, p1); u.y = pk2bf(p2, p3);                    \
          *(uint2*)&Pl[w][l16][quad * 4] = u; }                                 \
        { uint2 u; u.x = pk2bf(p4, p5); u.y = pk2bf(p6, p7);                    \
          *(uint2*)&Pl[w][l16][16 + quad * 4] = u; }                            \
        s16x8 pf = *(const s16x8*)&Pl[w][l16][quad * 8];                        \
        _Pragma("unroll") for (int t = 0; t < 4; t++)                           \
            o[si][t] = __builtin_amdgcn_mfma_f32_16x16x32_bf16(vf[t], pf, o[si][t], 0, 0, 0); \
    }

    LOADK(kfA, 0); LOADV(vfA, 0);
    for (int n0 = 0; n0 < N_; n0 += 64) {
        LOADK(kfB, n0 + 32); LOADV(vfB, n0 + 32);
        PROCESS(kfA, vfA);
        int nn = (n0 + 64) & (N_ - 1);
        LOADK(kfA, nn); LOADV(vfA, nn);
        PROCESS(kfB, vfB);
    }

    // epilogue: finish l, normalize, transpose O^T -> row-major via LDS, store bf16
    #pragma unroll
    for (int si = 0; si < 2; si++) {
        float lt = lp[si];
        lt += __shfl_xor(lt, 16, 64);
        lt += __shfl_xor(lt, 32, 64);
        float inv = 1.0f / lt;
        #pragma unroll
        for (int t = 0; t < 4; t++) {
            uint2 u;
            u.x = pk2bf(o[si][t][0] * inv, o[si][t][1] * inv);
            u.y = pk2bf(o[si][t][2] * inv, o[si][t][3] * inv);
            *(uint2*)&Ol[w][l16][t * 16 + quad * 4] = u;
        }
        s16x8 r0 = *(const s16x8*)&Ol[w][l16][quad * 16];
        s16x8 r1 = *(const s16x8*)&Ol[w][l16][quad * 16 + 8];
        size_t row = (size_t)b * N_ + m0 + si * 16 + l16;
        *(s16x8*)(Xb + row * DIM + h * HD + quad * 16) = r0;
        *(s16x8*)(Xb + row * DIM + h * HD + quad * 16 + 8) = r1;
    }
#undef LOADK
#undef LOADV
#undef PROCESS
}

// ---------------- Kernel 4: projection GEMM (8192x768x768) + bias ----------------
// grid: 128*12 blocks; block = 64x64 tile; wave = 32x32; register double-buffered K-loop
__global__ __launch_bounds__(256)
void proj_kernel(const unsigned short* __restrict__ Xb,
                 const unsigned short* __restrict__ Wb,
                 const float* __restrict__ pb,
                 float* __restrict__ out) {
    int bid = blockIdx.x;
    int bm = bid % 128, bn = bid / 128;   // same-bm blocks 128 apart -> same XCD (A reuse)
    int tid = threadIdx.x, w = tid >> 6, ln = tid & 63;
    int l16 = ln & 15, quad = ln >> 4;
    int m0 = bm * 64 + (w & 1) * 32;
    int n0 = bn * 64 + (w >> 1) * 32;

    const unsigned short* A0 = Xb + (size_t)(m0 + l16) * DIM + quad * 8;
    const unsigned short* A1 = A0 + (size_t)16 * DIM;
    const unsigned short* Bp0 = Wb + (size_t)(n0 + l16) * DIM + quad * 8;
    const unsigned short* Bp1 = Bp0 + (size_t)16 * DIM;

    f32x4 c[2][2];
    #pragma unroll
    for (int i = 0; i < 2; i++)
        #pragma unroll
        for (int j = 0; j < 2; j++) c[i][j] = (f32x4){0.f, 0.f, 0.f, 0.f};

    s16x8 aA[2], bA[2], aB[2], bB[2];
    aA[0] = *(const s16x8*)(A0);  aA[1] = *(const s16x8*)(A1);
    bA[0] = *(const s16x8*)(Bp0); bA[1] = *(const s16x8*)(Bp1);

    for (int kk = 0; kk < DIM; kk += 64) {
        int k1 = kk + 32;
        aB[0] = *(const s16x8*)(A0 + k1);  aB[1] = *(const s16x8*)(A1 + k1);
        bB[0] = *(const s16x8*)(Bp0 + k1); bB[1] = *(const s16x8*)(Bp1 + k1);
        #pragma unroll
        for (int i = 0; i < 2; i++)
            #pragma unroll
            for (int j = 0; j < 2; j++)
                c[i][j] = __builtin_amdgcn_mfma_f32_16x16x32_bf16(aA[i], bA[j], c[i][j], 0, 0, 0);
        int k2 = (kk + 64) % DIM;
        aA[0] = *(const s16x8*)(A0 + k2);  aA[1] = *(const s16x8*)(A1 + k2);
        bA[0] = *(const s16x8*)(Bp0 + k2); bA[1] = *(const s16x8*)(Bp1 + k2);
        #pragma unroll
        for (int i = 0; i < 2; i++)
            #pragma unroll
            for (int j = 0; j < 2; j++)
                c[i][j] = __builtin_amdgcn_mfma_f32_16x16x32_bf16(aB[i], bB[j], c[i][j], 0, 0, 0);
    }

    #pragma unroll
    for (int j = 0; j < 2; j++) {
        float bias = pb[n0 + j * 16 + l16];
        #pragma unroll
        for (int i = 0; i < 2; i++)
            #pragma unroll
            for (int r = 0; r < 4; r++) {
                int row = m0 + i * 16 + quad * 4 + r;
                out[(size_t)row * DIM + n0 + j * 16 + l16] = c[i][j][r] + bias;
            }
    }
}

extern "C" void kernel_launch(void* const* d_in, const int* in_sizes, int n_in,
                              void* d_out, int out_size, void* d_ws, size_t ws_size,
                              hipStream_t stream) {
    const float* QKV = (const float*)d_in[0];
    const float* qw  = (const float*)d_in[1];
    const float* qb  = (const float*)d_in[2];
    const float* kw  = (const float*)d_in[3];
    const float* kb  = (const float*)d_in[4];
    const float* pw  = (const float*)d_in[5];
    const float* pb  = (const float*)d_in[6];
    float* out = (float*)d_out;

    unsigned short* Qn = (unsigned short*)d_ws;                 // 96*1024*64
    unsigned short* Kn = Qn + (size_t)BH * N_ * HD;
    unsigned short* Vt = Kn + (size_t)BH * N_ * HD;
    unsigned short* Xb = Vt + (size_t)BH * N_ * HD;             // 8192*768
    unsigned short* Wb = Xb + (size_t)B_ * N_ * DIM;            // 768*768

    ln_pack_kernel<<<BH * 16, 256, 0, stream>>>(QKV, qw, qb, kw, kb, Qn, Kn, Vt);
    cvt_kernel<<<(DIM * DIM / 4 + 255) / 256, 256, 0, stream>>>(pw, Wb, DIM * DIM / 4);
    attn_kernel<<<BH * 8, 256, 0, stream>>>(Qn, Kn, Vt, Xb);
    proj_kernel<<<128 * 12, 256, 0, stream>>>(Xb, Wb, pb, out);
}